// Round 14
// baseline (302.833 us; speedup 1.0000x reference)
//
#include <hip/hip_runtime.h>

// LNKillingRelu: out = where(kf<=0, x, x + kf*d)
//   d[b,g,k,n]  = sum_f W[g,f] x[b,f,k,n]          (bf16 MFMA GEMM, K=512)
//   kf[b,g,n]   = sum_{k,l} x[b,g,k,n] G[k,l] d[b,g,l,n]   (fp32, G = sl3 Killing)
// x: [8,512,8,2048] f32, W: [512,512] f32, out same shape as x.
//
// R14 = R13 (persistent 16-slot LDS x-tile, A direct from L2-resident packed
// W, conflict-free staging writes, LDS bf16 epilogue) with the per-iter
// __syncthreads (vmcnt(0) block drain -- measured ~6.7k cy/iter vs ~2k of
// compute) replaced by a NON-DRAINING barrier:
//     s_waitcnt lgkmcnt(0) ; s_barrier
// Correctness needs only (a) cvt's source regs -- per-thread private, the
// compiler auto-inserts the register-dependency vmcnt wait before the cvt
// (no global_load_lds in the loop, so no R10-class ledger race), and
// (b) ds_write completion -- lgkmcnt(0). The x-prefetch tail no longer
// serializes all 16 waves each iteration. (Primitive proven correct in R4.)

typedef short bf16x8 __attribute__((ext_vector_type(8)));
typedef short bf16x4 __attribute__((ext_vector_type(4)));
typedef float f32x4 __attribute__((ext_vector_type(4)));

__device__ __forceinline__ unsigned short f2bf(float f) {
  unsigned int u = __float_as_uint(f);
  u += 0x7fffu + ((u >> 16) & 1u);   // round-to-nearest-even
  return (unsigned short)(u >> 16);
}

__device__ __forceinline__ float bfu(unsigned short u) {
  return __uint_as_float(((unsigned int)u) << 16);
}

__device__ __forceinline__ void block_sync_nodrain() {
  // LDS writes visible to the workgroup; vmcnt deliberately NOT drained:
  // private global prefetch loads stay in flight across the barrier.
  asm volatile("s_waitcnt lgkmcnt(0)" ::: "memory");
  __builtin_amdgcn_s_barrier();
  __builtin_amdgcn_sched_barrier(0);
}

// ---------------- prepass: pack W -> bf16 (512 KB) [R9/R11-proven] ----------
// chunk cid = (kt*4+kg)*512 + row ; elems j=0..7 -> f = kt*32 + kg*8 + j
__global__ __launch_bounds__(256) void prepack_w(const float* __restrict__ W,
                                                 short* __restrict__ wp) {
  const int cid = blockIdx.x * 256 + threadIdx.x;    // 32768 chunks
  const int row  = cid & 511;
  const int kgkt = cid >> 9;
  const int kg = kgkt & 3;
  const int kt = kgkt >> 2;
  const float* src = W + (size_t)row * 512 + kt * 32 + kg * 8;
  bf16x8 v;
#pragma unroll
  for (int j = 0; j < 8; ++j) v[j] = (short)f2bf(src[j]);
  *(bf16x8*)&wp[(size_t)cid * 8] = v;
}

// ---------------- main fused GEMM + Killing epilogue ----------------
__global__ __launch_bounds__(1024, 4) void lnkill_fullg5(
    const float* __restrict__ x, const short* __restrict__ wp,
    float* __restrict__ out) {
  // persistent x tile: slot kt = [kg(4)][c(128)][8 bf16], 8KB each, 128KB total
  __shared__ __align__(16) short ldsX[16][4096];

  const int tid   = threadIdx.x;
  const int lane  = tid & 63;
  const int w     = tid >> 6;      // wave 0..15; owns g-rows w*32..w*32+31
  const int klane = lane >> 4;     // kg 0..3
  const int li    = lane & 15;

  const int bid = blockIdx.x;      // 0..1023 (no cross-block x sharing)
  const int nt  = bid & 127;
  const int b   = bid >> 7;
  const int n0  = nt * 16;

  // staging map (conflict-free): thread writes 8B at byte tid*8 of the slot.
  //   kgs = tid>>8, cm = (tid>>1)&127, j0 = (tid&1)*4
  //   f = kt*32 + kgs*8 + j0 + jj ; k = cm>>4 ; n = n0 + (cm&15)
  const int kgs = tid >> 8;
  const int cm  = (tid >> 1) & 127;
  const int j0  = (tid & 1) * 4;
  const float* xs = x + (((size_t)(b * 512 + kgs * 8 + j0)) * 8 + (cm >> 4)) * 2048
                      + n0 + (cm & 15);
  const int bwr = tid * 4;         // shorts; == ((kgs*128+cm)*8 + j0)

  f32x4 acc[2][8] = {};            // [fm][fn]; fn == k plane
  float rB[2][4];                  // staged-x regsets; B(t) in rB[t&1]

  // ---- prologue ----
  {
    float b0[4];
#pragma unroll
    for (int jj = 0; jj < 4; ++jj) b0[jj] = xs[(size_t)jj * 16384];          // B(0)
#pragma unroll
    for (int jj = 0; jj < 4; ++jj) rB[1][jj] = xs[(size_t)(32 + jj) * 16384]; // B(1)
    bf16x4 v;    // implicit wait covers b0 only (rB[1] stays in flight)
#pragma unroll
    for (int jj = 0; jj < 4; ++jj) v[jj] = (short)f2bf(b0[jj]);
    *(bf16x4*)&ldsX[0][bwr] = v;
  }
  block_sync_nodrain();   // B(0) visible

#pragma unroll
  for (int kt = 0; kt < 16; ++kt) {
    // 1) cvt B(kt+1) -> slot kt+1 (fresh slot, no WAR). The cvt's source
    //    regs are private; compiler inserts the exact vmcnt wait needed.
    if (kt < 15) {
      bf16x4 v;
#pragma unroll
      for (int jj = 0; jj < 4; ++jj) v[jj] = (short)f2bf(rB[(kt + 1) & 1][jj]);
      *(bf16x4*)&ldsX[kt + 1][bwr] = v;
    }
    // 2) issue B(kt+2) loads -> rB[kt&1] (consumed next iter, after a full
    //    compute window in flight)
    if (kt < 14) {
#pragma unroll
      for (int jj = 0; jj < 4; ++jj)
        rB[kt & 1][jj] = xs[(size_t)((kt + 2) * 32 + jj) * 16384];
    }

    // 3) compute tile kt: A direct from L2-resident wp, B from slot kt
    const short* wt = wp + ((size_t)(kt * 4 + klane) * 512 + w * 32 + li) * 8;
    bf16x8 afr0 = *(const bf16x8*)(wt);
    bf16x8 afr1 = *(const bf16x8*)(wt + 128);   // +16 rows
    const short* Bc = ldsX[kt];
    bf16x8 bfr[8];
#pragma unroll
    for (int fn = 0; fn < 8; ++fn)
      bfr[fn] = *(const bf16x8*)&Bc[(klane * 128 + fn * 16 + li) * 8];
#pragma unroll
    for (int fn = 0; fn < 8; ++fn)
      acc[0][fn] = __builtin_amdgcn_mfma_f32_16x16x32_bf16(afr0, bfr[fn],
                                                           acc[0][fn], 0, 0, 0);
#pragma unroll
    for (int fn = 0; fn < 8; ++fn)
      acc[1][fn] = __builtin_amdgcn_mfma_f32_16x16x32_bf16(afr1, bfr[fn],
                                                           acc[1][fn], 0, 0, 0);

    // 4) non-draining barrier: slot kt+1 ds_writes complete (lgkmcnt) and
    //    visible; private prefetch loads stay in flight across it.
    if (kt < 15) block_sync_nodrain();
  }

  // ---- epilogue: kf (Killing Gram) + branch + store; x as bf16 from LDS ----
  // row g = w*32 + fm*16 + klane*4 + r lives in slot w:
  //   kg = fm*2 + (klane>>1), j = (klane&1)*4 + r, c = k*16 + li
  const unsigned short* xls = (const unsigned short*)&ldsX[w][0];
#pragma unroll
  for (int fm = 0; fm < 2; ++fm) {
#pragma unroll
    for (int r = 0; r < 4; ++r) {
      const int g = w * 32 + fm * 16 + klane * 4 + r;
      const size_t base = ((size_t)(b * 512 + g)) * 16384 + n0 + li;
      const int kgd = fm * 2 + (klane >> 1);
      const int jd  = (klane & 1) * 4 + r;
      float xk[8];
#pragma unroll
      for (int k = 0; k < 8; ++k)
        xk[k] = bfu(xls[(kgd * 128 + k * 16 + li) * 8 + jd]);
      // c_l = (G x)_l ; G: 12@(0,0),(4,4); -6@(0,4); 6@{1,3},{2,6},{5,7}
      const float c0 = 12.f * xk[0] - 6.f * xk[4];
      const float c4 = 12.f * xk[4] - 6.f * xk[0];
      const float c1 = 6.f * xk[3];
      const float c2 = 6.f * xk[6];
      const float c3 = 6.f * xk[1];
      const float c5 = 6.f * xk[7];
      const float c6 = 6.f * xk[2];
      const float c7 = 6.f * xk[5];
      const float kf = c0 * acc[fm][0][r] + c1 * acc[fm][1][r]
                     + c2 * acc[fm][2][r] + c3 * acc[fm][3][r]
                     + c4 * acc[fm][4][r] + c5 * acc[fm][5][r]
                     + c6 * acc[fm][6][r] + c7 * acc[fm][7][r];
#pragma unroll
      for (int k = 0; k < 8; ++k) {
        const float o = (kf <= 0.f) ? xk[k] : fmaf(kf, acc[fm][k][r], xk[k]);
        out[base + (size_t)k * 2048] = o;
      }
    }
  }
}

// ---------------- fallback: proven R2 kernel (ws too small) ----------------
__global__ __launch_bounds__(512, 4) void lnkill_fused(
    const float* __restrict__ x, const float* __restrict__ W,
    float* __restrict__ out) {
  __shared__ __align__(16) short ldsA[2][4096];
  __shared__ __align__(16) short ldsB[2][4096];

  const int tid  = threadIdx.x;
  const int lane = tid & 63;
  const int w    = tid >> 6;

  const int bid = blockIdx.x;
  const int l   = (bid & 7) * 512 + (bid >> 3);
  const int gt  = l & 3;
  const int nt  = (l >> 2) & 127;
  const int b   = l >> 9;
  const int g0  = gt * 128;
  const int n0  = nt * 16;

  const int cm = tid & 127;
  const int fg = tid >> 7;
  const float* xs   = x + (((size_t)(b * 512 + fg * 8)) * 8 + (cm >> 4)) * 2048
                        + n0 + (cm & 15);
  const float* Wrow = W + (size_t)(g0 + cm) * 512 + fg * 8;

  f32x4 acc[8] = {};

  {
    float xv[8];
#pragma unroll
    for (int j = 0; j < 8; ++j) xv[j] = xs[(size_t)j * 16384];
    float4 wv[2];
    const float4* wpp = (const float4*)Wrow;
    wv[0] = wpp[0]; wv[1] = wpp[1];
    const float* wf = (const float*)wv;
    bf16x8 vb, va;
#pragma unroll
    for (int j = 0; j < 8; ++j) {
      vb[j] = (short)f2bf(xv[j]);
      va[j] = (short)f2bf(wf[j]);
    }
    *(bf16x8*)&ldsB[0][(fg * 128 + cm) * 8] = vb;
    *(bf16x8*)&ldsA[0][(fg * 128 + cm) * 8] = va;
  }
  __syncthreads();

  const int klane = lane >> 4;
  const int li    = lane & 15;

  for (int kt = 0; kt < 16; ++kt) {
    const int cur = kt & 1;
    float xv[8];
    float4 wv[2];
    if (kt < 15) {
      const float* xpn = xs + (size_t)(kt + 1) * 32 * 16384;
#pragma unroll
      for (int j = 0; j < 8; ++j) xv[j] = xpn[(size_t)j * 16384];
      const float4* wpp = (const float4*)(Wrow + (kt + 1) * 32);
      wv[0] = wpp[0]; wv[1] = wpp[1];
    }
    {
      const short* Ac = ldsA[cur];
      const short* Bc = ldsB[cur];
      bf16x8 afr = *(const bf16x8*)&Ac[(klane * 128 + w * 16 + li) * 8];
#pragma unroll
      for (int fn = 0; fn < 8; ++fn) {
        bf16x8 bfr = *(const bf16x8*)&Bc[(klane * 128 + fn * 16 + li) * 8];
        acc[fn] = __builtin_amdgcn_mfma_f32_16x16x32_bf16(afr, bfr, acc[fn], 0, 0, 0);
      }
    }
    if (kt < 15) {
      const int nxt = cur ^ 1;
      const float* wf = (const float*)wv;
      bf16x8 vb, va;
#pragma unroll
      for (int j = 0; j < 8; ++j) {
        vb[j] = (short)f2bf(xv[j]);
        va[j] = (short)f2bf(wf[j]);
      }
      __syncthreads();
      *(bf16x8*)&ldsB[nxt][(fg * 128 + cm) * 8] = vb;
      *(bf16x8*)&ldsA[nxt][(fg * 128 + cm) * 8] = va;
      __syncthreads();
    }
  }

#pragma unroll
  for (int r = 0; r < 4; ++r) {
    const int g = g0 + w * 16 + klane * 4 + r;
    const size_t base = ((size_t)(b * 512 + g)) * 16384 + n0 + li;
    float xk[8];
#pragma unroll
    for (int k = 0; k < 8; ++k) xk[k] = x[base + (size_t)k * 2048];
    const float c0 = 12.f * xk[0] - 6.f * xk[4];
    const float c4 = 12.f * xk[4] - 6.f * xk[0];
    const float c1 = 6.f * xk[3];
    const float c2 = 6.f * xk[6];
    const float c3 = 6.f * xk[1];
    const float c5 = 6.f * xk[7];
    const float c6 = 6.f * xk[2];
    const float c7 = 6.f * xk[5];
    const float kf = c0 * acc[0][r] + c1 * acc[1][r]
                   + c2 * acc[2][r] + c3 * acc[3][r]
                   + c4 * acc[4][r] + c5 * acc[5][r]
                   + c6 * acc[6][r] + c7 * acc[7][r];
#pragma unroll
    for (int k = 0; k < 8; ++k) {
      const float o = (kf <= 0.f) ? xk[k] : fmaf(kf, acc[k][r], xk[k]);
      out[base + (size_t)k * 2048] = o;
    }
  }
}

extern "C" void kernel_launch(void* const* d_in, const int* in_sizes, int n_in,
                              void* d_out, int out_size, void* d_ws, size_t ws_size,
                              hipStream_t stream) {
  const float* x = (const float*)d_in[0];
  const float* W = (const float*)d_in[1];
  float* out = (float*)d_out;

  if (ws_size >= (size_t)524288) {
    short* wp = (short*)d_ws;                       // 512 KB packed W
    prepack_w<<<dim3(128), dim3(256), 0, stream>>>(W, wp);
    // 1024 blocks: 128 nt x 8 b ; 1024 thr (16 waves x 32 g-rows, full 512 g)
    lnkill_fullg5<<<dim3(1024), dim3(1024), 0, stream>>>(x, wp, out);
  } else {
    lnkill_fused<<<dim3(4096), dim3(512), 0, stream>>>(x, W, out);
  }
}

// Round 15
// 172.560 us; speedup vs baseline: 1.7549x; 1.7549x over previous
//
#include <hip/hip_runtime.h>

// LNKillingRelu: out = where(kf<=0, x, x + kf*d)
//   d[b,g,k,n]  = sum_f W[g,f] x[b,f,k,n]          (bf16 MFMA GEMM, K=512)
//   kf[b,g,n]   = sum_{k,l} x[b,g,k,n] G[k,l] d[b,g,l,n]   (fp32, G = sl3 Killing)
// x: [8,512,8,2048] f32, W: [512,512] f32, out same shape as x.
//
// R15 = R13 (persistent 16-slot LDS x-tile, A direct from L2-resident packed
// W, conflict-free staging, LDS bf16 epilogue, __syncthreads only) with the
// 16 per-iter barriers restructured into THREE PHASES with 2 barriers total:
//   A: stage slots 0-7 (per-thread private)           -- syncthreads --
//   B: kt=0..7: cvt+write slot kt+8 | load kt+10 | compute tile kt
//      (reads 0-7 / writes 8-15 disjoint; write-once slots -> no WAR)
//                                                     -- syncthreads --
//   C: kt=8..15: compute, no barriers (LDS read-only); epilogue.
// Staging of the 2nd half fully overlaps compute of the 1st half. Register
// footprint identical to R13 (rB[2][4], acc[2][8], static idx; NO asm, NO
// sched_barrier -- R14's regression was a reg-spill from exactly those).

typedef short bf16x8 __attribute__((ext_vector_type(8)));
typedef short bf16x4 __attribute__((ext_vector_type(4)));
typedef float f32x4 __attribute__((ext_vector_type(4)));

__device__ __forceinline__ unsigned short f2bf(float f) {
  unsigned int u = __float_as_uint(f);
  u += 0x7fffu + ((u >> 16) & 1u);   // round-to-nearest-even
  return (unsigned short)(u >> 16);
}

__device__ __forceinline__ float bfu(unsigned short u) {
  return __uint_as_float(((unsigned int)u) << 16);
}

// ---------------- prepass: pack W -> bf16 (512 KB) [R9/R11-proven] ----------
// chunk cid = (kt*4+kg)*512 + row ; elems j=0..7 -> f = kt*32 + kg*8 + j
__global__ __launch_bounds__(256) void prepack_w(const float* __restrict__ W,
                                                 short* __restrict__ wp) {
  const int cid = blockIdx.x * 256 + threadIdx.x;    // 32768 chunks
  const int row  = cid & 511;
  const int kgkt = cid >> 9;
  const int kg = kgkt & 3;
  const int kt = kgkt >> 2;
  const float* src = W + (size_t)row * 512 + kt * 32 + kg * 8;
  bf16x8 v;
#pragma unroll
  for (int j = 0; j < 8; ++j) v[j] = (short)f2bf(src[j]);
  *(bf16x8*)&wp[(size_t)cid * 8] = v;
}

// ---------------- main fused GEMM + Killing epilogue ----------------
__global__ __launch_bounds__(1024, 4) void lnkill_fullg6(
    const float* __restrict__ x, const short* __restrict__ wp,
    float* __restrict__ out) {
  // persistent x tile: slot kt = [kg(4)][c(128)][8 bf16], 8KB each, 128KB total
  __shared__ __align__(16) short ldsX[16][4096];

  const int tid   = threadIdx.x;
  const int lane  = tid & 63;
  const int w     = tid >> 6;      // wave 0..15; owns g-rows w*32..w*32+31
  const int klane = lane >> 4;     // kg 0..3
  const int li    = lane & 15;

  const int bid = blockIdx.x;      // 0..1023 (no cross-block x sharing)
  const int nt  = bid & 127;
  const int b   = bid >> 7;
  const int n0  = nt * 16;

  // staging map (conflict-free): thread writes 8B at byte tid*8 of the slot.
  //   kgs = tid>>8, cm = (tid>>1)&127, j0 = (tid&1)*4
  //   f = kt*32 + kgs*8 + j0 + jj ; k = cm>>4 ; n = n0 + (cm&15)
  const int kgs = tid >> 8;
  const int cm  = (tid >> 1) & 127;
  const int j0  = (tid & 1) * 4;
  const float* xs = x + (((size_t)(b * 512 + kgs * 8 + j0)) * 8 + (cm >> 4)) * 2048
                      + n0 + (cm & 15);
  const int bwr = tid * 4;         // shorts; == ((kgs*128+cm)*8 + j0)

  f32x4 acc[2][8] = {};            // [fm][fn]; fn == k plane
  float rB[2][4];                  // staged-x regsets; tile t in rB[t&1]

  // ---- phase A: stage slots 0..7 (per-thread private, no sync needed) ----
#pragma unroll
  for (int jj = 0; jj < 4; ++jj) rB[0][jj] = xs[(size_t)jj * 16384];        // t0
#pragma unroll
  for (int jj = 0; jj < 4; ++jj) rB[1][jj] = xs[(size_t)(32 + jj) * 16384]; // t1
#pragma unroll
  for (int t = 0; t < 8; ++t) {
    bf16x4 v;
#pragma unroll
    for (int jj = 0; jj < 4; ++jj) v[jj] = (short)f2bf(rB[t & 1][jj]);
    *(bf16x4*)&ldsX[t][bwr] = v;
    // issue loads for tile t+2 (t+2 <= 9; tiles 8,9 land in rB for phase B)
#pragma unroll
    for (int jj = 0; jj < 4; ++jj)
      rB[t & 1][jj] = xs[(size_t)((t + 2) * 32 + jj) * 16384];
  }
  __syncthreads();   // slots 0..7 visible; tiles 8,9 in regs

  // ---- phase B: compute 0..7 while staging slots 8..15 ----
#pragma unroll
  for (int kt = 0; kt < 8; ++kt) {
    // cvt tile kt+8 (loaded >=2 iters ago) -> fresh slot kt+8 (never read
    // before barrier 2 -> no WAR; writes are per-thread private until then)
    {
      bf16x4 v;
#pragma unroll
      for (int jj = 0; jj < 4; ++jj) v[jj] = (short)f2bf(rB[kt & 1][jj]);
      *(bf16x4*)&ldsX[kt + 8][bwr] = v;
    }
    // issue loads for tile kt+10 -> rB[kt&1]
    if (kt < 6) {
#pragma unroll
      for (int jj = 0; jj < 4; ++jj)
        rB[kt & 1][jj] = xs[(size_t)((kt + 10) * 32 + jj) * 16384];
    }
    // compute tile kt: A direct from L2-resident wp, B from slot kt
    const short* wt = wp + ((size_t)(kt * 4 + klane) * 512 + w * 32 + li) * 8;
    bf16x8 afr0 = *(const bf16x8*)(wt);
    bf16x8 afr1 = *(const bf16x8*)(wt + 128);   // +16 rows
    const short* Bc = ldsX[kt];
#pragma unroll
    for (int fn = 0; fn < 8; ++fn) {
      bf16x8 bfr = *(const bf16x8*)&Bc[(klane * 128 + fn * 16 + li) * 8];
      acc[0][fn] = __builtin_amdgcn_mfma_f32_16x16x32_bf16(afr0, bfr,
                                                           acc[0][fn], 0, 0, 0);
      acc[1][fn] = __builtin_amdgcn_mfma_f32_16x16x32_bf16(afr1, bfr,
                                                           acc[1][fn], 0, 0, 0);
    }
  }
  __syncthreads();   // slots 8..15 visible; ldsX read-only from here

  // ---- phase C: compute 8..15, no barriers ----
#pragma unroll
  for (int kt = 8; kt < 16; ++kt) {
    const short* wt = wp + ((size_t)(kt * 4 + klane) * 512 + w * 32 + li) * 8;
    bf16x8 afr0 = *(const bf16x8*)(wt);
    bf16x8 afr1 = *(const bf16x8*)(wt + 128);
    const short* Bc = ldsX[kt];
#pragma unroll
    for (int fn = 0; fn < 8; ++fn) {
      bf16x8 bfr = *(const bf16x8*)&Bc[(klane * 128 + fn * 16 + li) * 8];
      acc[0][fn] = __builtin_amdgcn_mfma_f32_16x16x32_bf16(afr0, bfr,
                                                           acc[0][fn], 0, 0, 0);
      acc[1][fn] = __builtin_amdgcn_mfma_f32_16x16x32_bf16(afr1, bfr,
                                                           acc[1][fn], 0, 0, 0);
    }
  }

  // ---- epilogue: kf (Killing Gram) + branch + store; x as bf16 from LDS ----
  // row g = w*32 + fm*16 + klane*4 + r lives in slot w:
  //   kg = fm*2 + (klane>>1), j = (klane&1)*4 + r, c = k*16 + li
  const unsigned short* xls = (const unsigned short*)&ldsX[w][0];
#pragma unroll
  for (int fm = 0; fm < 2; ++fm) {
#pragma unroll
    for (int r = 0; r < 4; ++r) {
      const int g = w * 32 + fm * 16 + klane * 4 + r;
      const size_t base = ((size_t)(b * 512 + g)) * 16384 + n0 + li;
      const int kgd = fm * 2 + (klane >> 1);
      const int jd  = (klane & 1) * 4 + r;
      float xk[8];
#pragma unroll
      for (int k = 0; k < 8; ++k)
        xk[k] = bfu(xls[(kgd * 128 + k * 16 + li) * 8 + jd]);
      // c_l = (G x)_l ; G: 12@(0,0),(4,4); -6@(0,4); 6@{1,3},{2,6},{5,7}
      const float c0 = 12.f * xk[0] - 6.f * xk[4];
      const float c4 = 12.f * xk[4] - 6.f * xk[0];
      const float c1 = 6.f * xk[3];
      const float c2 = 6.f * xk[6];
      const float c3 = 6.f * xk[1];
      const float c5 = 6.f * xk[7];
      const float c6 = 6.f * xk[2];
      const float c7 = 6.f * xk[5];
      const float kf = c0 * acc[fm][0][r] + c1 * acc[fm][1][r]
                     + c2 * acc[fm][2][r] + c3 * acc[fm][3][r]
                     + c4 * acc[fm][4][r] + c5 * acc[fm][5][r]
                     + c6 * acc[fm][6][r] + c7 * acc[fm][7][r];
#pragma unroll
      for (int k = 0; k < 8; ++k) {
        const float o = (kf <= 0.f) ? xk[k] : fmaf(kf, acc[fm][k][r], xk[k]);
        out[base + (size_t)k * 2048] = o;
      }
    }
  }
}

// ---------------- fallback: proven R2 kernel (ws too small) ----------------
__global__ __launch_bounds__(512, 4) void lnkill_fused(
    const float* __restrict__ x, const float* __restrict__ W,
    float* __restrict__ out) {
  __shared__ __align__(16) short ldsA[2][4096];
  __shared__ __align__(16) short ldsB[2][4096];

  const int tid  = threadIdx.x;
  const int lane = tid & 63;
  const int w    = tid >> 6;

  const int bid = blockIdx.x;
  const int l   = (bid & 7) * 512 + (bid >> 3);
  const int gt  = l & 3;
  const int nt  = (l >> 2) & 127;
  const int b   = l >> 9;
  const int g0  = gt * 128;
  const int n0  = nt * 16;

  const int cm = tid & 127;
  const int fg = tid >> 7;
  const float* xs   = x + (((size_t)(b * 512 + fg * 8)) * 8 + (cm >> 4)) * 2048
                        + n0 + (cm & 15);
  const float* Wrow = W + (size_t)(g0 + cm) * 512 + fg * 8;

  f32x4 acc[8] = {};

  {
    float xv[8];
#pragma unroll
    for (int j = 0; j < 8; ++j) xv[j] = xs[(size_t)j * 16384];
    float4 wv[2];
    const float4* wpp = (const float4*)Wrow;
    wv[0] = wpp[0]; wv[1] = wpp[1];
    const float* wf = (const float*)wv;
    bf16x8 vb, va;
#pragma unroll
    for (int j = 0; j < 8; ++j) {
      vb[j] = (short)f2bf(xv[j]);
      va[j] = (short)f2bf(wf[j]);
    }
    *(bf16x8*)&ldsB[0][(fg * 128 + cm) * 8] = vb;
    *(bf16x8*)&ldsA[0][(fg * 128 + cm) * 8] = va;
  }
  __syncthreads();

  const int klane = lane >> 4;
  const int li    = lane & 15;

  for (int kt = 0; kt < 16; ++kt) {
    const int cur = kt & 1;
    float xv[8];
    float4 wv[2];
    if (kt < 15) {
      const float* xpn = xs + (size_t)(kt + 1) * 32 * 16384;
#pragma unroll
      for (int j = 0; j < 8; ++j) xv[j] = xpn[(size_t)j * 16384];
      const float4* wpp = (const float4*)(Wrow + (kt + 1) * 32);
      wv[0] = wpp[0]; wv[1] = wpp[1];
    }
    {
      const short* Ac = ldsA[cur];
      const short* Bc = ldsB[cur];
      bf16x8 afr = *(const bf16x8*)&Ac[(klane * 128 + w * 16 + li) * 8];
#pragma unroll
      for (int fn = 0; fn < 8; ++fn) {
        bf16x8 bfr = *(const bf16x8*)&Bc[(klane * 128 + fn * 16 + li) * 8];
        acc[fn] = __builtin_amdgcn_mfma_f32_16x16x32_bf16(afr, bfr, acc[fn], 0, 0, 0);
      }
    }
    if (kt < 15) {
      const int nxt = cur ^ 1;
      const float* wf = (const float*)wv;
      bf16x8 vb, va;
#pragma unroll
      for (int j = 0; j < 8; ++j) {
        vb[j] = (short)f2bf(xv[j]);
        va[j] = (short)f2bf(wf[j]);
      }
      __syncthreads();
      *(bf16x8*)&ldsB[nxt][(fg * 128 + cm) * 8] = vb;
      *(bf16x8*)&ldsA[nxt][(fg * 128 + cm) * 8] = va;
      __syncthreads();
    }
  }

#pragma unroll
  for (int r = 0; r < 4; ++r) {
    const int g = g0 + w * 16 + klane * 4 + r;
    const size_t base = ((size_t)(b * 512 + g)) * 16384 + n0 + li;
    float xk[8];
#pragma unroll
    for (int k = 0; k < 8; ++k) xk[k] = x[base + (size_t)k * 2048];
    const float c0 = 12.f * xk[0] - 6.f * xk[4];
    const float c4 = 12.f * xk[4] - 6.f * xk[0];
    const float c1 = 6.f * xk[3];
    const float c2 = 6.f * xk[6];
    const float c3 = 6.f * xk[1];
    const float c5 = 6.f * xk[7];
    const float c6 = 6.f * xk[2];
    const float c7 = 6.f * xk[5];
    const float kf = c0 * acc[0][r] + c1 * acc[1][r]
                   + c2 * acc[2][r] + c3 * acc[3][r]
                   + c4 * acc[4][r] + c5 * acc[5][r]
                   + c6 * acc[6][r] + c7 * acc[7][r];
#pragma unroll
    for (int k = 0; k < 8; ++k) {
      const float o = (kf <= 0.f) ? xk[k] : fmaf(kf, acc[k][r], xk[k]);
      out[base + (size_t)k * 2048] = o;
    }
  }
}

extern "C" void kernel_launch(void* const* d_in, const int* in_sizes, int n_in,
                              void* d_out, int out_size, void* d_ws, size_t ws_size,
                              hipStream_t stream) {
  const float* x = (const float*)d_in[0];
  const float* W = (const float*)d_in[1];
  float* out = (float*)d_out;

  if (ws_size >= (size_t)524288) {
    short* wp = (short*)d_ws;                       // 512 KB packed W
    prepack_w<<<dim3(128), dim3(256), 0, stream>>>(W, wp);
    // 1024 blocks: 128 nt x 8 b ; 1024 thr (16 waves x 32 g-rows, full 512 g)
    lnkill_fullg6<<<dim3(1024), dim3(1024), 0, stream>>>(x, wp, out);
  } else {
    lnkill_fused<<<dim3(4096), dim3(512), 0, stream>>>(x, W, out);
  }
}